// Round 3
// baseline (341.288 us; speedup 1.0000x reference)
//
#include <hip/hip_runtime.h>
#include <hip/hip_bf16.h>
#include <math.h>

typedef __hip_bfloat16 bf16;
typedef unsigned short u16;
typedef __attribute__((ext_vector_type(8))) short bf16x8;
typedef __attribute__((ext_vector_type(4))) float f32x4;
typedef __attribute__((ext_vector_type(16))) float f32x16;
typedef __attribute__((ext_vector_type(4))) unsigned u32x4;

__device__ __forceinline__ float us2f(u16 u) { return __uint_as_float(((unsigned)u) << 16); }
__device__ __forceinline__ u16 f2us(float f) { bf16 h = __float2bfloat16(f); return *(u16*)&h; }

__device__ __forceinline__ float wave_bcast_sum(float v) {
#pragma unroll
    for (int off = 32; off > 0; off >>= 1) v += __shfl_down(v, off);
    return __shfl(v, 0);
}

// async global->LDS, 16B per lane. LDS dest is wave-uniform base (+lane*16 by HW).
__device__ __forceinline__ void glds16(const u16* g, u16* l) {
    __builtin_amdgcn_global_load_lds((const __attribute__((address_space(1))) void*)g,
                                     (__attribute__((address_space(3))) void*)l, 16, 0, 0);
}

// ---------------------------------------------------------------------------
// f32 -> bf16 elementwise conversion (for weights)
// ---------------------------------------------------------------------------
__global__ __launch_bounds__(256) void k_f2b(const float* __restrict__ in, u16* __restrict__ out, int n) {
    int i = blockIdx.x * 256 + threadIdx.x;
    if (i < n) out[i] = f2us(in[i]);
}

// ---------------------------------------------------------------------------
// Precompute attention bias table biasT[h][m][n] = rpb[relidx(n,m)]*log2(e).
// m,n padded 343->352 (pad = 0; pad keys killed via lab=255 in k_attn).
// m-major so k_attn's per-(chunk,r) loads are coalesced across n=lane&31.
// ---------------------------------------------------------------------------
__global__ __launch_bounds__(256) void k_bias(const float* __restrict__ rpb, float* __restrict__ bt) {
    int idx = blockIdx.x * 256 + threadIdx.x;
    if (idx >= 6 * 352 * 352) return;
    int h = idx / (352 * 352);
    int r = idx - h * (352 * 352);
    int m = r / 352, n = r - m * 352;
    float v = 0.0f;
    if (m < 343 && n < 343) {
        int ni = n / 49, nr = n - ni * 49, nj = nr / 7, nk = nr - nj * 7;
        int mi = m / 49, mr = m - mi * 49, mj = mr / 7, mk = mr - mj * 7;
        int d = (ni - mi) * 169 + (nj - mj) * 13 + (nk - mk) + 1098;
        v = rpb[d * 6 + h] * 1.4426950408889634f;
    }
    bt[idx] = v;
}

// ---------------------------------------------------------------------------
// LN1 + roll(-3,-3,-3) + window partition. f32 in -> bf16 out (window order).
// ---------------------------------------------------------------------------
__global__ __launch_bounds__(256) void k_ln1_winpart(
    const float* __restrict__ x, const float* __restrict__ g, const float* __restrict__ b,
    u16* __restrict__ out)
{
    int lane = threadIdx.x & 63;
    int t = blockIdx.x * 4 + (threadIdx.x >> 6);
    int bidx = t / (64 * 343);
    int r = t - bidx * (64 * 343);
    int w = r / 343;
    int n = r - w * 343;
    int wd = w >> 4, wh = (w >> 2) & 3, ww = w & 3;
    int i = n / 49, rem = n - i * 49;
    int j = rem / 7, k = rem - j * 7;
    int sd = wd * 7 + i + 3; if (sd >= 28) sd -= 28;
    int sh = wh * 7 + j + 3; if (sh >= 28) sh -= 28;
    int sw = ww * 7 + k + 3; if (sw >= 28) sw -= 28;
    size_t src = ((((size_t)bidx * 28 + sd) * 28 + sh) * 28 + sw) * 192;
    float v0 = x[src + lane], v1 = x[src + lane + 64], v2 = x[src + lane + 128];
    float s  = wave_bcast_sum(v0 + v1 + v2);
    float mu = s * (1.0f / 192.0f);
    float s2 = wave_bcast_sum(v0 * v0 + v1 * v1 + v2 * v2);
    float rs = rsqrtf(s2 * (1.0f / 192.0f) - mu * mu + 1e-5f);
    u16* op = out + (size_t)t * 192;
    op[lane]       = f2us((v0 - mu) * rs * g[lane]       + b[lane]);
    op[lane + 64]  = f2us((v1 - mu) * rs * g[lane + 64]  + b[lane + 64]);
    op[lane + 128] = f2us((v2 - mu) * rs * g[lane + 128] + b[lane + 128]);
}

// ---------------------------------------------------------------------------
// Fused: window reverse + roll(+3) + residual add (f32 x1 out) + LN2 (bf16 out)
// ---------------------------------------------------------------------------
__global__ __launch_bounds__(256) void k_add_winrev_ln2(
    const float* __restrict__ x, const u16* __restrict__ projw,
    const float* __restrict__ g, const float* __restrict__ b,
    float* __restrict__ x1, u16* __restrict__ h2)
{
    int lane = threadIdx.x & 63;
    int t = blockIdx.x * 4 + (threadIdx.x >> 6);
    int sw_ = t % 28, t1 = t / 28;
    int sh_ = t1 % 28, t2 = t1 / 28;
    int sd_ = t2 % 28, bidx = t2 / 28;
    int rd = sd_ + 25; if (rd >= 28) rd -= 28;   // (d-3) mod 28
    int rh = sh_ + 25; if (rh >= 28) rh -= 28;
    int rw = sw_ + 25; if (rw >= 28) rw -= 28;
    int wd = rd / 7, i = rd - wd * 7;
    int wh = rh / 7, j = rh - wh * 7;
    int ww = rw / 7, k = rw - ww * 7;
    int w = (wd << 4) + (wh << 2) + ww;
    int n = (i * 7 + j) * 7 + k;
    size_t src = (((size_t)(bidx * 64 + w)) * 343 + n) * 192;
    const float* xp = x + (size_t)t * 192;
    float v0 = xp[lane]       + us2f(projw[src + lane]);
    float v1 = xp[lane + 64]  + us2f(projw[src + lane + 64]);
    float v2 = xp[lane + 128] + us2f(projw[src + lane + 128]);
    float* op = x1 + (size_t)t * 192;
    op[lane] = v0; op[lane + 64] = v1; op[lane + 128] = v2;
    float s  = wave_bcast_sum(v0 + v1 + v2);
    float mu = s * (1.0f / 192.0f);
    float s2 = wave_bcast_sum(v0 * v0 + v1 * v1 + v2 * v2);
    float rs = rsqrtf(s2 * (1.0f / 192.0f) - mu * mu + 1e-5f);
    u16* hp = h2 + (size_t)t * 192;
    hp[lane]       = f2us((v0 - mu) * rs * g[lane]       + b[lane]);
    hp[lane + 64]  = f2us((v1 - mu) * rs * g[lane + 64]  + b[lane + 64]);
    hp[lane + 128] = f2us((v2 - mu) * rs * g[lane + 128] + b[lane + 128]);
}

// ---------------------------------------------------------------------------
// MFMA GEMM, 2-phase double-buffered (T3 minimum recipe):
// prologue stage(0); loop: issue stage(t+1) -> ds_read+MFMA tile t ->
// vmcnt(0)+barrier. One barrier per K-step; next tile's loads overlap compute.
// out[m,n] = epi( sum_k A[m,k]*W[n,k] + bias[n] ). BM=128, BN=64, BK=32.
// ---------------------------------------------------------------------------
template<int ACT, int OUT>
__global__ __launch_bounds__(256) void k_gemm_mfma(
    const u16* __restrict__ A, const u16* __restrict__ W, const float* __restrict__ bias,
    u16* __restrict__ outB, float* __restrict__ outF, const float* __restrict__ resid,
    int M, int Nc, int K)
{
    __shared__ __align__(16) u16 As[2][128 * 32];
    __shared__ __align__(16) u16 Bs[2][64 * 32];
    int tid = threadIdx.x;
    int lane = tid & 63, wv = tid >> 6;
    int quad = lane >> 4, l16 = lane & 15;
    int m0 = blockIdx.y << 7, n0 = blockIdx.x << 6;

    f32x4 acc[2][4] = {};
    int rowA0 = tid >> 2;                 // 0..63
    int rowA1 = rowA0 + 64;               // 64..127
    int koff = (tid & 3) << 3;            // 0,8,16,24

    const u16* gA0 = A + (size_t)(m0 + rowA0) * K + koff;
    const u16* gA1 = A + (size_t)(m0 + rowA1) * K + koff;
    const u16* gB0 = W + (size_t)(n0 + rowA0) * K + koff;

    int nt = K >> 5;
    // prologue: stage tile 0 into buf 0
    glds16(gA0, &As[0][wv * 512]);
    glds16(gA1, &As[0][2048 + wv * 512]);
    glds16(gB0, &Bs[0][wv * 512]);
    asm volatile("s_waitcnt vmcnt(0)" ::: "memory");
    __builtin_amdgcn_s_barrier();

    int cur = 0;
    for (int t = 0; t < nt; ++t) {
        if (t + 1 < nt) {                 // issue next tile (overlaps compute)
            int k1 = (t + 1) << 5;
            glds16(gA0 + k1, &As[cur ^ 1][wv * 512]);
            glds16(gA1 + k1, &As[cur ^ 1][2048 + wv * 512]);
            glds16(gB0 + k1, &Bs[cur ^ 1][wv * 512]);
        }
        bf16x8 af[2], bfr[4];
#pragma unroll
        for (int mt = 0; mt < 2; mt++)
            af[mt] = *(const bf16x8*)&As[cur][(wv * 32 + mt * 16 + l16) * 32 + quad * 8];
#pragma unroll
        for (int nt2 = 0; nt2 < 4; nt2++)
            bfr[nt2] = *(const bf16x8*)&Bs[cur][(nt2 * 16 + l16) * 32 + quad * 8];
#pragma unroll
        for (int mt = 0; mt < 2; mt++)
#pragma unroll
            for (int nt2 = 0; nt2 < 4; nt2++)
                acc[mt][nt2] = __builtin_amdgcn_mfma_f32_16x16x32_bf16(af[mt], bfr[nt2], acc[mt][nt2], 0, 0, 0);
        asm volatile("s_waitcnt vmcnt(0)" ::: "memory");  // next tile landed
        __builtin_amdgcn_s_barrier();
        cur ^= 1;
    }
#pragma unroll
    for (int mt = 0; mt < 2; mt++) {
#pragma unroll
        for (int nt2 = 0; nt2 < 4; nt2++) {
#pragma unroll
            for (int r = 0; r < 4; r++) {
                int m = m0 + wv * 32 + mt * 16 + quad * 4 + r;
                int n = n0 + nt2 * 16 + l16;
                float v = acc[mt][nt2][r] + bias[n];
                if (ACT == 1) v = 0.5f * v * (1.0f + erff(v * 0.70710678118654752f));
                size_t off = (size_t)m * Nc + n;
                if (OUT == 1) outB[off] = f2us(v);
                else outF[off] = resid[off] + v;
            }
        }
    }
}

// ---------------------------------------------------------------------------
// Fused windowed attention, 32x32x16 MFMA + swapped QK^T (m214/T12 recipe).
// One block = (head, window, batch); 4 waves; wave owns 32-query tiles
// tile = wv, wv+4, wv+8 (<11); N padded 343->352.
// QK^T = mfma(K,Q): lane holds p[r]=P[n=lane&31][m=crow(r,hi)],
// crow(r,hi)=(r&3)+8*(r>>2)+4*hi. P->PV A-frags built IN-REGISTER via
// 8 packed-bf16 words + 4 v_permlane32_swap_b32 (no LDS round-trip).
// Ks stride 40 u16 (16B-aligned b128, 4-pass bank tiling), Vt stride 360.
// Bias from biasT[h][m][n] (xlog2e), mask via packed label compare.
// ---------------------------------------------------------------------------
__global__ __launch_bounds__(256) void k_attn(
    const u16* __restrict__ qkv, const float* __restrict__ biasT, u16* __restrict__ o_win)
{
    int head = blockIdx.x;
    int w = blockIdx.y;
    int bidx = blockIdx.z;
    __shared__ __align__(16) u16 Ks[352 * 40];
    __shared__ __align__(16) u16 Vt[32 * 360];
    __shared__ float invs[4][32];
    __shared__ unsigned char lab[352];
    int tid = threadIdx.x;
    int lane = tid & 63, wv = tid >> 6;
    int hi = lane >> 5, l31 = lane & 31;
    size_t base = ((size_t)(bidx * 64 + w)) * 343;

    // Stage K (stride 40) and V transposed (Vt[d][m], stride 360), zero pad.
    for (int i = tid; i < 2816; i += 256) {
        int m = i >> 3;
        int d4 = (i & 7) << 2;
        ushort4 kv = {0, 0, 0, 0}, vv = {0, 0, 0, 0};
        if (m < 343) {
            size_t off = (base + m) * 576 + head * 32 + d4;
            kv = *(const ushort4*)(qkv + off + 192);
            vv = *(const ushort4*)(qkv + off + 384);
        }
        *(ushort4*)&Ks[m * 40 + d4] = kv;
        Vt[(d4 + 0) * 360 + m] = vv.x;
        Vt[(d4 + 1) * 360 + m] = vv.y;
        Vt[(d4 + 2) * 360 + m] = vv.z;
        Vt[(d4 + 3) * 360 + m] = vv.w;
    }
    int wd = w >> 4, wh = (w >> 2) & 3, ww = w & 3;
    for (int n = tid; n < 352; n += 256) {
        unsigned char lv = 255;                      // pad rows never match
        if (n < 343) {
            int i = n / 49, rem = n - i * 49;
            int j = rem / 7, k = rem - j * 7;
            int gd = wd * 7 + i, gh = wh * 7 + j, gw = ww * 7 + k;
            int ld_ = (gd < 21) ? 0 : ((gd < 25) ? 1 : 2);
            int lh_ = (gh < 21) ? 0 : ((gh < 25) ? 1 : 2);
            int lw_ = (gw < 21) ? 0 : ((gw < 25) ? 1 : 2);
            lv = (unsigned char)(ld_ * 9 + lh_ * 3 + lw_);
        }
        lab[n] = lv;
    }
    __syncthreads();

    const float SL = 0.17677669529663687f * 1.4426950408889634f;  // scale*log2e
    const f32x16 z16 = {0,0,0,0,0,0,0,0,0,0,0,0,0,0,0,0};

    for (int tile = wv; tile < 11; tile += 4) {
        int n0 = tile * 32;
        int nq = n0 + l31; if (nq > 342) nq = 342;
        const u16* qp = qkv + (base + nq) * 576 + head * 32;
        bf16x8 bq0 = *(const bf16x8*)(qp + hi * 8);        // Q[n=l31][d=hi*8+j]
        bf16x8 bq1 = *(const bf16x8*)(qp + 16 + hi * 8);   // d=16+hi*8+j
        unsigned lr = lab[n0 + l31];
        const float* bq = biasT + (size_t)head * 352 * 352 + n0 + l31;

        f32x16 o = z16;
        float psum = 0.0f;
        for (int c = 0; c < 11; ++c) {
            int mb = c * 32;
            // QK^T (swapped): A=K rows m, B=Q cols n -> s[r]=P-score[n=l31][m=mb+crow(r,hi)]
            const u16* kp = &Ks[(mb + l31) * 40 + hi * 8];
            bf16x8 ka0 = *(const bf16x8*)kp;
            bf16x8 ka1 = *(const bf16x8*)(kp + 16);
            f32x16 s = __builtin_amdgcn_mfma_f32_32x32x16_bf16(ka0, bq0, z16, 0, 0, 0);
            s = __builtin_amdgcn_mfma_f32_32x32x16_bf16(ka1, bq1, s, 0, 0, 0);
            // labels for the 16 m rows this lane holds: m = mb + 4*hi + 8*g + q
            unsigned labw[4];
#pragma unroll
            for (int g = 0; g < 4; ++g)
                labw[g] = *(const unsigned*)&lab[mb + hi * 4 + g * 8];
            float p[16];
#pragma unroll
            for (int r = 0; r < 16; ++r) {
                int g = r >> 2, q = r & 3;
                float bb = bq[(size_t)(mb + 4 * hi + 8 * g + q) * 352];
                float e = exp2f(fmaf(s[r], SL, bb));
                p[r] = (((labw[g] >> (8 * q)) & 255u) == lr) ? e : 0.0f;
                psum += p[r];
            }
            // pack p -> bf16 pairs (m ascending within each u32)
            unsigned pk0 = (unsigned)f2us(p[0])  | ((unsigned)f2us(p[1])  << 16);
            unsigned pk1 = (unsigned)f2us(p[2])  | ((unsigned)f2us(p[3])  << 16);
            unsigned pk2 = (unsigned)f2us(p[4])  | ((unsigned)f2us(p[5])  << 16);
            unsigned pk3 = (unsigned)f2us(p[6])  | ((unsigned)f2us(p[7])  << 16);
            unsigned pk4 = (unsigned)f2us(p[8])  | ((unsigned)f2us(p[9])  << 16);
            unsigned pk5 = (unsigned)f2us(p[10]) | ((unsigned)f2us(p[11]) << 16);
            unsigned pk6 = (unsigned)f2us(p[12]) | ((unsigned)f2us(p[13]) << 16);
            unsigned pk7 = (unsigned)f2us(p[14]) | ((unsigned)f2us(p[15]) << 16);
            // cross-half exchange: after swap, {pk0,pk1,pk2,pk3} is the PV
            // A-frag for m-local 0..15, {pk4..pk7} for m-local 16..31.
            asm volatile("v_permlane32_swap_b32 %0, %1" : "+v"(pk0), "+v"(pk2));
            asm volatile("v_permlane32_swap_b32 %0, %1" : "+v"(pk1), "+v"(pk3));
            asm volatile("v_permlane32_swap_b32 %0, %1" : "+v"(pk4), "+v"(pk6));
            asm volatile("v_permlane32_swap_b32 %0, %1" : "+v"(pk5), "+v"(pk7));
            u32x4 A1 = {pk0, pk1, pk2, pk3};
            u32x4 A2 = {pk4, pk5, pk6, pk7};
            bf16x8 pa0 = __builtin_bit_cast(bf16x8, A1);
            bf16x8 pa1 = __builtin_bit_cast(bf16x8, A2);
            // PV: B=V[m][d=l31] from Vt
            const u16* vp = &Vt[l31 * 360 + mb + hi * 8];
            bf16x8 vb0 = *(const bf16x8*)vp;
            bf16x8 vb1 = *(const bf16x8*)(vp + 16);
            o = __builtin_amdgcn_mfma_f32_32x32x16_bf16(pa0, vb0, o, 0, 0, 0);
            o = __builtin_amdgcn_mfma_f32_32x32x16_bf16(pa1, vb1, o, 0, 0, 0);
        }
        // total row sum: own half + partner half
        psum += __shfl_xor(psum, 32);
        float inv = 1.0f / psum;
        invs[wv][l31] = inv;                         // wave-local
        asm volatile("s_waitcnt lgkmcnt(0)" ::: "memory");
        __builtin_amdgcn_sched_barrier(0);
#pragma unroll
        for (int r = 0; r < 16; ++r) {
            int crow = (r & 3) + 8 * (r >> 2) + 4 * hi;
            int n = n0 + crow;
            if (n < 343) {
                u16* op = o_win + (base + n) * 192 + head * 32;
                op[l31] = f2us(o[r] * invs[wv][crow]);
            }
        }
    }
}

// ---------------------------------------------------------------------------
extern "C" void kernel_launch(void* const* d_in, const int* in_sizes, int n_in,
                              void* d_out, int out_size, void* d_ws, size_t ws_size,
                              hipStream_t stream)
{
    const float* x      = (const float*)d_in[0];
    const float* ln1_g  = (const float*)d_in[1];
    const float* ln1_b  = (const float*)d_in[2];
    const float* qkv_w  = (const float*)d_in[3];
    const float* qkv_b  = (const float*)d_in[4];
    const float* rpb    = (const float*)d_in[5];
    const float* proj_w = (const float*)d_in[6];
    const float* proj_b = (const float*)d_in[7];
    const float* ln2_g  = (const float*)d_in[8];
    const float* ln2_b  = (const float*)d_in[9];
    const float* fc1_w  = (const float*)d_in[10];
    const float* fc1_b  = (const float*)d_in[11];
    const float* fc2_w  = (const float*)d_in[12];
    const float* fc2_b  = (const float*)d_in[13];

    const int M = 43904;                   // tokens = B*nW*N (343 x 128-row tiles)
    const size_t MC  = (size_t)M * 192;
    const size_t MC2 = MC * 2;             // bytes of a bf16 [M,192] buffer

    // ws layout (peak 67.4MB, unchanged):
    //   hA    [0, 16.9MB)              bf16 [M,192]: hwin -> owin -> h2
    //   qkvb  [16.9, 67.4MB)           bf16 [M,576]; dead after attn, then:
    //     projw [16.9, 33.8MB) / gbuf [16.9, 50.7MB) / fc weights at [51MB,...)
    // d_out scratch phase 1: qkv_wb/proj_wb at [0,295KB), biasT f32 [4MB, 7MB)
    char* ws = (char*)d_ws;
    u16* hA     = (u16*)ws;
    u16* qkvb   = (u16*)(ws + MC2);
    u16* projw  = (u16*)(ws + MC2);
    u16* gbuf   = (u16*)(ws + MC2);
    u16* fc1_wb = (u16*)(ws + 51u * 1024 * 1024);
    u16* fc2_wb = (u16*)(ws + 51u * 1024 * 1024 + 294912);
    float* out  = (float*)d_out;
    u16* qkv_wb  = (u16*)d_out;            // 110592 u16
    u16* proj_wb = (u16*)d_out + 110592;   //  36864 u16
    float* biasT = (float*)((char*)d_out + 4u * 1024 * 1024);  // 743424 f32 = 2.97MB

    // Phase 1: weights->bf16, bias table, LN1, QKV (MFMA), attention
    k_f2b<<<432, 256, 0, stream>>>(qkv_w, qkv_wb, 110592);
    k_f2b<<<144, 256, 0, stream>>>(proj_w, proj_wb, 36864);
    k_bias<<<2904, 256, 0, stream>>>(rpb, biasT);
    k_ln1_winpart<<<M / 4, 256, 0, stream>>>(x, ln1_g, ln1_b, hA);
    k_gemm_mfma<0, 1><<<dim3(9, 343), 256, 0, stream>>>(hA, qkv_wb, qkv_b, qkvb, nullptr, nullptr, M, 576, 192);
    k_attn<<<dim3(6, 64, 2), 256, 0, stream>>>(qkvb, biasT, hA);
    // fc weights into dead qkvb tail (must be after attn)
    k_f2b<<<576, 256, 0, stream>>>(fc1_w, fc1_wb, 147456);
    k_f2b<<<576, 256, 0, stream>>>(fc2_w, fc2_wb, 147456);
    // proj (MFMA), fused window-reverse + residual + LN2
    k_gemm_mfma<0, 1><<<dim3(3, 343), 256, 0, stream>>>(hA, proj_wb, proj_b, projw, nullptr, nullptr, M, 192, 192);
    k_add_winrev_ln2<<<M / 4, 256, 0, stream>>>(x, projw, ln2_g, ln2_b, out, hA);
    // Phase 2: MLP (MFMA), 2 chunks (172 + 171 row-tiles)
    const int CH0 = 22016, CH1 = 21888;
    k_gemm_mfma<1, 1><<<dim3(12, 172), 256, 0, stream>>>(hA, fc1_wb, fc1_b, gbuf, nullptr, nullptr, CH0, 768, 192);
    k_gemm_mfma<0, 2><<<dim3(3, 172), 256, 0, stream>>>(gbuf, fc2_wb, fc2_b, nullptr, out, out, CH0, 192, 768);
    k_gemm_mfma<1, 1><<<dim3(12, 171), 256, 0, stream>>>(hA + (size_t)CH0 * 192, fc1_wb, fc1_b, gbuf, nullptr, nullptr, CH1, 768, 192);
    k_gemm_mfma<0, 2><<<dim3(3, 171), 256, 0, stream>>>(gbuf, fc2_wb, fc2_b, nullptr, out + (size_t)CH0 * 192, out + (size_t)CH0 * 192, CH1, 192, 768);
}